// Round 8
// baseline (1350.651 us; speedup 1.0000x reference)
//
#include <hip/hip_runtime.h>
#include <hip/hip_bf16.h>
#include <math.h>

using bf16 = __hip_bfloat16;

#define NB 4
#define C_ 96
#define NPIX 36864
#define IMG 9216
#define CH_ST 9216
#define N_ST 884736
#define HID 255
#define EPSF 1e-5f
#define TOT 3538944
#define RNPIX (1.f / 36864.f)

// ---------------------------------------------------------------- LayerNorm
// block = 4 channel-quarters x 64 pixels; x cached in 24 regs (single read).
__global__ __launch_bounds__(256) void ln_kernel(const float* __restrict__ X,
                                                 float* __restrict__ Y,
                                                 const float* __restrict__ w,
                                                 const float* __restrict__ b) {
  __shared__ float red[2][4][64];
  __shared__ float wb[192];
  int tid = threadIdx.x;
  if (tid < 192) wb[tid] = (tid < 96) ? w[tid] : b[tid - 96];
  int cq = tid >> 6, px = tid & 63;
  int pix = blockIdx.x * 64 + px;
  int n = pix / IMG, p = pix % IMG;
  const float* xp = X + (long)n * N_ST + (long)(cq * 24) * CH_ST + p;
  float xr[24];
  float s = 0.f, sq = 0.f;
  #pragma unroll
  for (int k = 0; k < 24; k++) {
    float v = xp[(long)k * CH_ST];
    xr[k] = v; s += v; sq += v * v;
  }
  red[0][cq][px] = s; red[1][cq][px] = sq;
  __syncthreads();
  float S  = red[0][0][px] + red[0][1][px] + red[0][2][px] + red[0][3][px];
  float SQ = red[1][0][px] + red[1][1][px] + red[1][2][px] + red[1][3][px];
  float m = S * (1.f / C_);
  float r = rsqrtf(fmaxf(SQ * (1.f / C_) - m * m, 0.f) + EPSF);
  float* yp = Y + (long)n * N_ST + (long)(cq * 24) * CH_ST + p;
  #pragma unroll
  for (int k = 0; k < 24; k++)
    yp[(long)k * CH_ST] = (xr[k] - m) * r * wb[cq * 24 + k] + wb[96 + cq * 24 + k];
}

// ------------------------------------------- transpose NCHW -> [c][n][w][h]
__global__ void trans_kernel(const float* __restrict__ Y0, float* __restrict__ Y0C) {
  __shared__ float T[32][33];
  int nc = blockIdx.z; int n = nc / C_, c = nc % C_;
  int h0 = blockIdx.x * 32, w0 = blockIdx.y * 32;
  int tx = threadIdx.x, ty = threadIdx.y;
  const float* src = Y0 + (long)n * N_ST + (long)c * CH_ST;
  for (int r = 0; r < 4; r++)
    T[ty + 8 * r][tx] = src[(h0 + ty + 8 * r) * 96 + w0 + tx];
  __syncthreads();
  float* dst = Y0C + (long)c * NPIX + (long)n * IMG;
  for (int r = 0; r < 4; r++)
    dst[(w0 + ty + 8 * r) * 96 + h0 + tx] = T[tx][ty + 8 * r];
}

// ---------------------------------------------------------------- generic GEMM
// STATS=1: accumulate per-row (s, sq) partials into rsum[0..191]/rsum[192..383]
template<int TM, int TN, int EPI, int STATS>
__global__ __launch_bounds__(256) void gemm_kernel(
    const float* __restrict__ A, const float* __restrict__ B,
    float* __restrict__ Cout, int M, int K, int NperZ,
    long bCstride, long bZstride, int batch,
    const float* __restrict__ X1, float* __restrict__ OutF,
    float* __restrict__ rsum) {
  constexpr int NT = TN / 16;
  constexpr int RT = TM / 16;
  __shared__ float As[32][TM];
  __shared__ float Bs[32][TN + 4];
  const int tx = threadIdx.x, ty = threadIdx.y;
  const int tid = ty * 16 + tx;
  const int m0 = blockIdx.y * TM;
  const int q0 = blockIdx.x * TN;
  const int z  = blockIdx.z;
  const float* Bz = B + (long)z * bZstride;
  float acc[RT][NT];
  #pragma unroll
  for (int a = 0; a < RT; a++)
    #pragma unroll
    for (int b = 0; b < NT; b++) acc[a][b] = 0.f;

  for (int kk = 0; kk < K; kk += 32) {
    #pragma unroll
    for (int it = 0; it < (32 * TM) / 256; it++) {
      int i = tid + it * 256;
      int c = i / TM, r = i % TM;
      int mm = m0 + r, kc = kk + c;
      As[c][r] = (mm < M && kc < K) ? A[(long)mm * K + kc] : 0.f;
    }
    #pragma unroll
    for (int it = 0; it < (32 * TN) / 256; it++) {
      int i = tid + it * 256;
      int c = i / TN, q = i % TN;
      int kc = kk + c;
      Bs[c][q] = (kc < K) ? Bz[(long)kc * bCstride + q0 + q] : 0.f;
    }
    __syncthreads();
    for (int kc = 0; kc < 32; kc++) {
      float av[RT];
      if constexpr (RT % 4 == 0) {
        #pragma unroll
        for (int u = 0; u < RT / 4; u++) {
          float4 a4 = *(const float4*)&As[kc][ty * RT + 4 * u];
          av[4 * u] = a4.x; av[4 * u + 1] = a4.y; av[4 * u + 2] = a4.z; av[4 * u + 3] = a4.w;
        }
      } else {
        #pragma unroll
        for (int u = 0; u < RT / 2; u++) {
          float2 a2 = *(const float2*)&As[kc][ty * RT + 2 * u];
          av[2 * u] = a2.x; av[2 * u + 1] = a2.y;
        }
      }
      float bv[NT];
      #pragma unroll
      for (int v4 = 0; v4 < NT / 4; v4++) {
        float4 b4 = *(const float4*)&Bs[kc][v4 * 64 + tx * 4];
        bv[v4 * 4] = b4.x; bv[v4 * 4 + 1] = b4.y; bv[v4 * 4 + 2] = b4.z; bv[v4 * 4 + 3] = b4.w;
      }
      #pragma unroll
      for (int a = 0; a < RT; a++)
        #pragma unroll
        for (int b = 0; b < NT; b++)
          acc[a][b] = fmaf(av[a], bv[b], acc[a][b]);
    }
    __syncthreads();
  }
  const long oStride = (long)NperZ * gridDim.z;
  if (EPI == 0) {
    #pragma unroll
    for (int a = 0; a < RT; a++) {
      int mm = m0 + ty * RT + a;
      if (mm < M) {
        float* dst = Cout + (long)mm * oStride + (long)z * NperZ + q0;
        #pragma unroll
        for (int v4 = 0; v4 < NT / 4; v4++)
          *(float4*)(dst + v4 * 64 + tx * 4) =
              make_float4(acc[a][v4 * 4], acc[a][v4 * 4 + 1],
                          acc[a][v4 * 4 + 2], acc[a][v4 * 4 + 3]);
      }
    }
  } else {
    #pragma unroll
    for (int a = 0; a < RT; a++) {
      int mm = m0 + ty * RT + a;
      if (mm < M) {
        #pragma unroll
        for (int v4 = 0; v4 < NT / 4; v4++) {
          int Q = q0 + v4 * 64 + tx * 4;
          int n = batch + z + Q / IMG, p = Q % IMG;
          long base = (long)n * N_ST + (long)mm * CH_ST + p;
          #pragma unroll
          for (int b = 0; b < 4; b++)
            OutF[base + b] = acc[a][v4 * 4 + b] + X1[base + b];
        }
      }
    }
  }
  if (STATS) {
    #pragma unroll
    for (int a = 0; a < RT; a++) {
      int mm = m0 + ty * RT + a;
      float s = 0.f, sq = 0.f;
      #pragma unroll
      for (int b = 0; b < NT; b++) { float v = acc[a][b]; s += v; sq += v * v; }
      #pragma unroll
      for (int off = 8; off; off >>= 1) {
        s += __shfl_down(s, off, 16); sq += __shfl_down(sq, off, 16);
      }
      if (tx == 0 && mm < M) {
        atomicAdd(&rsum[mm], s);
        atomicAdd(&rsum[192 + mm], sq);
      }
    }
  }
}

// ---------------- rel window tables; block 0 also re-zeros out_sum
__global__ void relstat_kernel(const float* __restrict__ relp, float* __restrict__ tbl,
                               float* __restrict__ osum) {
  int i = threadIdx.x;
  if (blockIdx.x == 0)
    for (int t = i; t < 384; t += 96) osum[t] = 0.f;
  if (i >= 96) return;
  int side = blockIdx.x / 27, row = blockIdx.x % 27;
  const float* base = relp + side * 6 * 191;
  float* T = tbl + side * 27 * 96;
  if (row < 6) {
    float s = 0.f;
    for (int d = 0; d < 96; d++) s += base[row * 191 + i + d];
    T[row * 96 + i] = s;
  } else {
    int p = row - 6, c = 0;
    while (p >= 6 - c) { p -= 6 - c; c++; }
    int c2 = c + p;
    float s = 0.f;
    for (int d = 0; d < 96; d++) s += base[c * 191 + i + d] * base[c2 * 191 + i + d];
    T[576 + (row - 6) * 96 + i] = s;
  }
}

// ---------------- algebraic sim stats (Gram identity); aff computed inline
__global__ __launch_bounds__(256) void simstat2_kernel(const float* __restrict__ QKV,
                                                       const float* __restrict__ qsum,
                                                       const float* __restrict__ gq,
                                                       const float* __restrict__ bq,
                                                       const float* __restrict__ tbl,
                                                       float* __restrict__ stats) {
  int g = blockIdx.x & 7, chunk = blockIdx.x >> 3;
  int bbg = threadIdx.x >> 5, lane = threadIdx.x & 31;
  int bb = chunk * 8 + bbg;
  const float* Aq = tbl;
  const float* Wq = tbl + 6 * 96;
  const float* Ak = tbl + 27 * 96;
  const float* Wk = tbl + 27 * 96 + 6 * 96;
  float qa[6], qb[6], ka[6], kb[6];
  #pragma unroll
  for (int c = 0; c < 6; c++) {
    int oq = g * 24 + c, ok = g * 24 + 6 + c;
    float m1 = qsum[oq] * RNPIX;
    float v1 = fmaxf(qsum[192 + oq] * RNPIX - m1 * m1, 0.f);
    qa[c] = gq[oq] * rsqrtf(v1 + EPSF); qb[c] = bq[oq] - m1 * qa[c];
    float m2 = qsum[ok] * RNPIX;
    float v2 = fmaxf(qsum[192 + ok] * RNPIX - m2 * m2, 0.f);
    ka[c] = gq[ok] * rsqrtf(v2 + EPSF); kb[c] = bq[ok] - m2 * ka[c];
  }
  float Sq[6] = {}, Sk[6] = {}, Gq[21] = {}, Gk[21] = {};
  float lq = 0.f, lsq = 0.f, lk = 0.f, lsk = 0.f;
  #pragma unroll
  for (int ii = 0; ii < 3; ii++) {
    int i = lane + 32 * ii;
    float qv[6], kv[6];
    #pragma unroll
    for (int c = 0; c < 6; c++) {
      int oq = g * 24 + c, ok = g * 24 + 6 + c;
      qv[c] = QKV[(long)oq * NPIX + bb * 96 + i] * qa[c] + qb[c];
      kv[c] = QKV[(long)ok * NPIX + bb * 96 + i] * ka[c] + kb[c];
      Sq[c] += qv[c]; Sk[c] += kv[c];
      lq = fmaf(qv[c], Aq[c * 96 + i], lq);
      lk = fmaf(kv[c], Ak[c * 96 + i], lk);
    }
    int p = 0;
    #pragma unroll
    for (int c = 0; c < 6; c++)
      #pragma unroll
      for (int c2 = c; c2 < 6; c2++, p++) {
        float f = (c == c2) ? 1.f : 2.f;
        float pq = qv[c] * qv[c2], pk = kv[c] * kv[c2];
        Gq[p] += pq; Gk[p] += pk;
        lsq = fmaf(pq * f, Wq[p * 96 + i], lsq);
        lsk = fmaf(pk * f, Wk[p * 96 + i], lsk);
      }
  }
  #pragma unroll
  for (int off = 16; off; off >>= 1) {
    #pragma unroll
    for (int c = 0; c < 6; c++) { Sq[c] += __shfl_down(Sq[c], off, 32); Sk[c] += __shfl_down(Sk[c], off, 32); }
    #pragma unroll
    for (int p = 0; p < 21; p++) { Gq[p] += __shfl_down(Gq[p], off, 32); Gk[p] += __shfl_down(Gk[p], off, 32); }
    lq += __shfl_down(lq, off, 32);  lsq += __shfl_down(lsq, off, 32);
    lk += __shfl_down(lk, off, 32);  lsk += __shfl_down(lsk, off, 32);
  }
  __shared__ float red[6];
  if (threadIdx.x < 6) red[threadIdx.x] = 0.f;
  __syncthreads();
  if (lane == 0) {
    float sqk = 0.f, sqk2 = 0.f;
    #pragma unroll
    for (int c = 0; c < 6; c++) sqk += Sq[c] * Sk[c];
    int p = 0;
    #pragma unroll
    for (int c = 0; c < 6; c++)
      #pragma unroll
      for (int c2 = c; c2 < 6; c2++, p++)
        sqk2 += ((c == c2) ? 1.f : 2.f) * Gq[p] * Gk[p];
    atomicAdd(&red[0], sqk); atomicAdd(&red[3], sqk2);
    atomicAdd(&red[1], lq);  atomicAdd(&red[4], lsq);
    atomicAdd(&red[2], lk);  atomicAdd(&red[5], lsk);
  }
  __syncthreads();
  if (threadIdx.x < 3) {
    atomicAdd(&stats[(threadIdx.x * 8 + g) * 2 + 0], red[threadIdx.x]);
    atomicAdd(&stats[(threadIdx.x * 8 + g) * 2 + 1], red[threadIdx.x + 3]);
  }
}

__global__ void simfin_kernel(const float* __restrict__ stats,
                              const float* __restrict__ gsim,
                              float* __restrict__ scale) {
  int t = threadIdx.x;
  if (t < 24) {
    float cnt = 384.f * 9216.f;
    float m = stats[t * 2] / cnt;
    float var = fmaxf(stats[t * 2 + 1] / cnt - m * m, 0.f);
    scale[t] = gsim[t] * rsqrtf(var + EPSF);
  }
}

// ------------------- attention v4: aff from raw sums; 4-wave softmax;
// phase-3 accumulates output row stats (replaces rowstat dispatch).
__global__ __launch_bounds__(256) void attn_kernel(const float* __restrict__ QKV,
                                                   const float* __restrict__ qsum,
                                                   const float* __restrict__ gq,
                                                   const float* __restrict__ bq,
                                                   const float* __restrict__ relp,
                                                   const float* __restrict__ sscale,
                                                   float* __restrict__ osum,
                                                   float* __restrict__ OutPre) {
  int blk = blockIdx.x;          // 3072 = 384 bb x 8 g
  int bb = blk >> 3, g = blk & 7;
  __shared__ float qF[6][96];
  __shared__ float kF[6][96];
  __shared__ float vF[12][96];
  __shared__ float rl[24 * 191];
  __shared__ float P[32][100];   // P[r][96] = rinv
  __shared__ float2 aff_s[24];
  int tid = threadIdx.x;
  float s0 = sscale[g], s1 = sscale[8 + g], s2 = sscale[16 + g];
  if (tid < 24) {
    int o = g * 24 + tid;
    float m = qsum[o] * RNPIX;
    float var = fmaxf(qsum[192 + o] * RNPIX - m * m, 0.f);
    float sc = gq[o] * rsqrtf(var + EPSF);
    aff_s[tid] = make_float2(sc, bq[o] - m * sc);
  }
  __syncthreads();
  // ---- staging (vectorized, once per (bb,g)) ----
  for (int i = tid; i < 288; i += 256) {         // q then k
    int half = i / 144, r = i % 144;
    int c = r / 24, qd = r % 24;
    float2 a = aff_s[half * 6 + c];
    int o = g * 24 + half * 6 + c;
    float4 v = *(const float4*)(QKV + (long)o * NPIX + bb * 96 + qd * 4);
    float4 w = make_float4(v.x * a.x + a.y, v.y * a.x + a.y,
                           v.z * a.x + a.y, v.w * a.x + a.y);
    if (half == 0) *(float4*)&qF[c][qd * 4] = w;
    else           *(float4*)&kF[c][qd * 4] = w;
  }
  for (int i = tid; i < 288; i += 256) {         // v
    int c = i / 24, qd = i % 24;
    float2 a = aff_s[12 + c];
    int o = g * 24 + 12 + c;
    float4 v = *(const float4*)(QKV + (long)o * NPIX + bb * 96 + qd * 4);
    *(float4*)&vF[c][qd * 4] = make_float4(v.x * a.x + a.y, v.y * a.x + a.y,
                                           v.z * a.x + a.y, v.w * a.x + a.y);
  }
  for (int i = tid; i < 1146; i += 256) {        // rl
    int e = i * 4;
    float4 v = *(const float4*)(relp + e);
    float4 w;
    w.x = v.x * ((e + 0) < 1146 ? s1 : (e + 0) < 2292 ? s2 : 1.f);
    w.y = v.y * ((e + 1) < 1146 ? s1 : (e + 1) < 2292 ? s2 : 1.f);
    w.z = v.z * ((e + 2) < 1146 ? s1 : (e + 2) < 2292 ? s2 : 1.f);
    w.w = v.w * ((e + 3) < 1146 ? s1 : (e + 3) < 2292 ? s2 : 1.f);
    *(float4*)&rl[e] = w;
  }
  __syncthreads();
  int hw = tid >> 5, l32 = tid & 31;
  float kreg[6][3];
  #pragma unroll
  for (int c = 0; c < 6; c++)
    #pragma unroll
    for (int j = 0; j < 3; j++) kreg[c][j] = kF[c][l32 * 3 + j];
  for (int iq = 0; iq < 3; iq++) {
    int i0 = iq * 32;
    // phase 1
    {
      int til = hw * 4;
      int ti = i0 + til;
      int tj = l32 * 3;
      int d0 = ti - tj + 93;
      int e0 = tj - ti + 92;
      float ap[4][3] = {};
      #pragma unroll
      for (int c = 0; c < 6; c++) {
        float4 q4 = *(const float4*)&qF[c][ti];
        float qv[4] = {q4.x, q4.y, q4.z, q4.w};
        float kv0[3], rq[6], rk[6];
        #pragma unroll
        for (int j = 0; j < 3; j++) kv0[j] = s0 * kreg[c][j];
        #pragma unroll
        for (int u = 0; u < 6; u++) { rq[u] = rl[c * 191 + d0 + u]; rk[u] = rl[(6 + c) * 191 + e0 + u]; }
        #pragma unroll
        for (int ii = 0; ii < 4; ii++)
          #pragma unroll
          for (int jj = 0; jj < 3; jj++) {
            ap[ii][jj] = fmaf(qv[ii], kv0[jj], ap[ii][jj]);
            ap[ii][jj] = fmaf(qv[ii], rq[ii - jj + 2], ap[ii][jj]);
            ap[ii][jj] = fmaf(kreg[c][jj], rk[jj - ii + 3], ap[ii][jj]);
          }
      }
      #pragma unroll
      for (int ii = 0; ii < 4; ii++)
        #pragma unroll
        for (int jj = 0; jj < 3; jj++)
          P[til + ii][l32 * 3 + jj] = ap[ii][jj];
    }
    __syncthreads();
    // phase 2: softmax, all 4 waves; row = (tid>>6)*8 + ((tid>>3)&7), 12 cols/lane
    {
      int wv = tid >> 6, rloc = (tid >> 3) & 7, l8 = tid & 7;
      int r = wv * 8 + rloc;
      float* Pr = &P[r][l8 * 12];
      float4 v0 = *(const float4*)(Pr);
      float4 v1 = *(const float4*)(Pr + 4);
      float4 v2 = *(const float4*)(Pr + 8);
      float mx = fmaxf(fmaxf(fmaxf(v0.x, v0.y), fmaxf(v0.z, v0.w)),
                 fmaxf(fmaxf(fmaxf(v1.x, v1.y), fmaxf(v1.z, v1.w)),
                       fmaxf(fmaxf(v2.x, v2.y), fmaxf(v2.z, v2.w))));
      #pragma unroll
      for (int off = 4; off; off >>= 1) mx = fmaxf(mx, __shfl_xor(mx, off, 8));
      v0 = make_float4(__expf(v0.x - mx), __expf(v0.y - mx), __expf(v0.z - mx), __expf(v0.w - mx));
      v1 = make_float4(__expf(v1.x - mx), __expf(v1.y - mx), __expf(v1.z - mx), __expf(v1.w - mx));
      v2 = make_float4(__expf(v2.x - mx), __expf(v2.y - mx), __expf(v2.z - mx), __expf(v2.w - mx));
      float s = v0.x + v0.y + v0.z + v0.w + v1.x + v1.y + v1.z + v1.w
              + v2.x + v2.y + v2.z + v2.w;
      #pragma unroll
      for (int off = 4; off; off >>= 1) s += __shfl_xor(s, off, 8);
      *(float4*)(Pr)     = v0;
      *(float4*)(Pr + 4) = v1;
      *(float4*)(Pr + 8) = v2;
      if (l8 == 0) P[r][96] = 1.f / s;
    }
    __syncthreads();
    // phase 3 + output-row stats
    {
      int orr0 = hw * 3;
      float acc3[3] = {};
      for (int jq = 0; jq < 24; jq++) {
        int j0 = jq * 4;
        float4 pv = *(const float4*)&P[l32][j0];
        #pragma unroll
        for (int u = 0; u < 3; u++) {
          int orr = orr0 + u, cc = orr >> 1;
          if ((orr & 1) == 0) {
            float4 vv = *(const float4*)&vF[cc][j0];
            acc3[u] += pv.x * vv.x + pv.y * vv.y + pv.z * vv.z + pv.w * vv.w;
          } else {
            const float* rv = &rl[(12 + cc) * 191];
            int bse = (i0 + l32) - j0 + 92;
            float f0 = rv[bse], f1 = rv[bse + 1], f2 = rv[bse + 2], f3 = rv[bse + 3];
            acc3[u] += pv.w * f0 + pv.z * f1 + pv.y * f2 + pv.x * f3;
          }
        }
      }
      float ri = P[l32][96];
      #pragma unroll
      for (int u = 0; u < 3; u++) {
        float ov = acc3[u] * ri;
        OutPre[(long)(g * 24 + orr0 + u) * NPIX + bb * 96 + i0 + l32] = ov;
        float sv = ov, sqv = ov * ov;
        #pragma unroll
        for (int off = 16; off; off >>= 1) {
          sv += __shfl_down(sv, off, 32); sqv += __shfl_down(sqv, off, 32);
        }
        if (l32 == 0) {
          atomicAdd(&osum[g * 24 + orr0 + u], sv);
          atomicAdd(&osum[192 + g * 24 + orr0 + u], sqv);
        }
      }
    }
    __syncthreads();
  }
}

// -------- pass1 BN-apply + pair-sum + transpose; block(0,0,0) zeros qkv sums
__global__ void apply1_kernel(const float* __restrict__ OutPre,
                              const float* __restrict__ osum,
                              const float* __restrict__ gout,
                              const float* __restrict__ bout,
                              float* __restrict__ qsum,
                              float* __restrict__ Y1) {
  __shared__ float T[32][33];
  int tx = threadIdx.x, ty = threadIdx.y;
  if (blockIdx.x == 0 && blockIdx.y == 0 && blockIdx.z == 0) {
    for (int t = ty * 32 + tx; t < 384; t += 256) qsum[t] = 0.f;
  }
  int z = blockIdx.z; int n = z / C_, cf = z % C_;
  int h0 = blockIdx.x * 32, w0 = blockIdx.y * 32;
  int o0 = 2 * cf, o1 = 2 * cf + 1;
  float m0 = osum[o0] * RNPIX;
  float a0x = gout[o0] * rsqrtf(fmaxf(osum[192 + o0] * RNPIX - m0 * m0, 0.f) + EPSF);
  float a0y = bout[o0] - m0 * a0x;
  float m1 = osum[o1] * RNPIX;
  float a1x = gout[o1] * rsqrtf(fmaxf(osum[192 + o1] * RNPIX - m1 * m1, 0.f) + EPSF);
  float a1y = bout[o1] - m1 * a1x;
  const float* r0 = OutPre + (long)o0 * NPIX + (long)n * IMG;
  const float* r1 = OutPre + (long)o1 * NPIX + (long)n * IMG;
  for (int r = 0; r < 4; r++) {
    int w = w0 + ty + 8 * r;
    int idx = w * 96 + h0 + tx;
    T[ty + 8 * r][tx] = (r0[idx] * a0x + a0y) + (r1[idx] * a1x + a1y);
  }
  __syncthreads();
  float* dst = Y1 + (long)n * N_ST + (long)cf * CH_ST;
  for (int r = 0; r < 4; r++)
    dst[(h0 + ty + 8 * r) * 96 + w0 + tx] = T[tx][ty + 8 * r];
}

// -------- pass2 BN-apply + pair-sum + residual with x
__global__ __launch_bounds__(256) void apply2_kernel(const float* __restrict__ OutPre,
                                                     const float* __restrict__ osum,
                                                     const float* __restrict__ gout,
                                                     const float* __restrict__ bout,
                                                     const float* __restrict__ X,
                                                     float* __restrict__ X1out) {
  int idx = blockIdx.x * 256 + threadIdx.x;
  if (idx >= TOT) return;
  int n = idx / N_ST;
  int rem = idx % N_ST;
  int cf = rem / CH_ST;
  int p = rem % CH_ST;
  long off = (long)n * IMG + p;
  int o0 = 2 * cf, o1 = 2 * cf + 1;
  float m0 = osum[o0] * RNPIX;
  float a0x = gout[o0] * rsqrtf(fmaxf(osum[192 + o0] * RNPIX - m0 * m0, 0.f) + EPSF);
  float a0y = bout[o0] - m0 * a0x;
  float m1 = osum[o1] * RNPIX;
  float a1x = gout[o1] * rsqrtf(fmaxf(osum[192 + o1] * RNPIX - m1 * m1, 0.f) + EPSF);
  float a1y = bout[o1] - m1 * a1x;
  float v = OutPre[(long)o0 * NPIX + off] * a0x + a0y
          + OutPre[(long)o1 * NPIX + off] * a1x + a1y
          + X[idx];
  X1out[idx] = v;
}

// ---------------- depthwise 3x3 SAME + GEGLU, per-batch slice
__global__ __launch_bounds__(256) void dwglu_kernel(const float* __restrict__ H,
                                                    const float* __restrict__ Wdw,
                                                    float* __restrict__ Gout) {
  int idx = blockIdx.x * 256 + threadIdx.x;
  if (idx >= HID * IMG) return;
  int c = idx / IMG;
  int p = idx % IMG, y = p / 96, x = p % 96;
  const float* h1 = H + (long)c * IMG;
  const float* h2 = H + (long)(c + HID) * IMG;
  const float* w1 = Wdw + c * 9;
  const float* w2 = Wdw + (c + HID) * 9;
  float acc1 = 0.f, acc2 = 0.f;
  #pragma unroll
  for (int dy = -1; dy <= 1; dy++) {
    int yy = y + dy; if (yy < 0 || yy >= 96) continue;
    #pragma unroll
    for (int dx = -1; dx <= 1; dx++) {
      int xx = x + dx; if (xx < 0 || xx >= 96) continue;
      int wi = (dy + 1) * 3 + dx + 1;
      acc1 = fmaf(h1[yy * 96 + xx], w1[wi], acc1);
      acc2 = fmaf(h2[yy * 96 + xx], w2[wi], acc2);
    }
  }
  float ge = 0.5f * acc1 * (1.f + erff(acc1 * 0.70710678118654752f));
  Gout[idx] = ge * acc2;
}

// ============================================================== launcher
extern "C" void kernel_launch(void* const* d_in, const int* in_sizes, int n_in,
                              void* d_out, int out_size, void* d_ws, size_t ws_size,
                              hipStream_t stream) {
  const float* x       = (const float*)d_in[0];
  const float* ln1w    = (const float*)d_in[1];
  const float* ln1b    = (const float*)d_in[2];
  const float* h_wqkv  = (const float*)d_in[3];
  const float* h_gqkv  = (const float*)d_in[4];
  const float* h_bqkv  = (const float*)d_in[5];
  const float* h_rel   = (const float*)d_in[6];
  const float* h_gsim  = (const float*)d_in[7];
  const float* h_gout  = (const float*)d_in[9];
  const float* h_bout  = (const float*)d_in[10];
  const float* w_wqkv  = (const float*)d_in[11];
  const float* w_gqkv  = (const float*)d_in[12];
  const float* w_bqkv  = (const float*)d_in[13];
  const float* w_rel   = (const float*)d_in[14];
  const float* w_gsim  = (const float*)d_in[15];
  const float* w_gout  = (const float*)d_in[17];
  const float* w_bout  = (const float*)d_in[18];
  const float* ln2w    = (const float*)d_in[19];
  const float* ln2b    = (const float*)d_in[20];
  const float* ffn_win = (const float*)d_in[21];
  const float* ffn_wdw = (const float*)d_in[22];
  const float* ffn_wout= (const float*)d_in[23];
  float* out = (float*)d_out;

  float* ws = (float*)d_ws;
  float* P = ws;
  float* Q = ws + 3538944;
  float* R = ws + 7077888;
  float* S = ws + 14155776;
  float* Gall = R;
  float* Hbuf = ws + 16478208;
  float* stats = ws + 21233664;
  const size_t need_bytes = (21233664ull + 8192ull) * 4ull;
  if (ws_size < need_bytes) return;

  float* qkv_sum = stats;          // [384]: s / sq
  float* out_sum = stats + 384;    // [384]
  float* sim_st  = stats + 768;
  float* sim_sc  = stats + 864;
  float* tbl     = stats + 1024;

  hipMemsetAsync(stats, 0, 8192 * sizeof(float), stream);

  dim3 b256(256), b1616(16, 16), b328(32, 8);

  ln_kernel<<<576, b256, 0, stream>>>(x, P, ln1w, ln1b);
  trans_kernel<<<dim3(3, 3, 384), b328, 0, stream>>>(P, Q);

  // ---- pass 1 (attention along H) ----
  gemm_kernel<96, 128, 0, 1><<<dim3(288, 2, 1), b1616, 0, stream>>>(h_wqkv, Q, R,
      192, 96, 36864, 36864L, 0L, 0, nullptr, nullptr, qkv_sum);
  relstat_kernel<<<54, 96, 0, stream>>>(h_rel, tbl, out_sum);
  simstat2_kernel<<<384, b256, 0, stream>>>(R, qkv_sum, h_gqkv, h_bqkv, tbl, sim_st);
  simfin_kernel<<<1, 32, 0, stream>>>(sim_st, h_gsim, sim_sc);
  attn_kernel<<<3072, b256, 0, stream>>>(R, qkv_sum, h_gqkv, h_bqkv, h_rel, sim_sc, out_sum, S);
  apply1_kernel<<<dim3(3, 3, 384), b328, 0, stream>>>(S, out_sum, h_gout, h_bout, qkv_sum, P);

  // ---- pass 2 (attention along W) ----
  gemm_kernel<96, 128, 0, 1><<<dim3(72, 2, 4), b1616, 0, stream>>>(w_wqkv, P, R,
      192, 96, 9216, 9216L, 884736L, 0, nullptr, nullptr, qkv_sum);
  relstat_kernel<<<54, 96, 0, stream>>>(w_rel, tbl, out_sum);   // re-zeros out_sum
  simstat2_kernel<<<384, b256, 0, stream>>>(R, qkv_sum, w_gqkv, w_bqkv, tbl, sim_st + 48);
  simfin_kernel<<<1, 32, 0, stream>>>(sim_st + 48, w_gsim, sim_sc + 24);
  attn_kernel<<<3072, b256, 0, stream>>>(R, qkv_sum, w_gqkv, w_bqkv, w_rel, sim_sc + 24, out_sum, S);
  apply2_kernel<<<13824, b256, 0, stream>>>(S, out_sum, w_gout, w_bout, x, P);

  // ---- FFN ----
  ln_kernel<<<576, b256, 0, stream>>>(P, Q, ln2w, ln2b);
  for (int n = 0; n < NB; n++) {
    gemm_kernel<128, 64, 0, 0><<<dim3(144, 4, 1), b1616, 0, stream>>>(ffn_win, Q + (long)n * N_ST, Hbuf,
        510, 96, 9216, 9216L, 0L, 0, nullptr, nullptr, nullptr);
    dwglu_kernel<<<9180, b256, 0, stream>>>(Hbuf, ffn_wdw, Gall + (long)n * 2350080);
  }
  gemm_kernel<96, 64, 1, 0><<<dim3(144, 1, 4), b1616, 0, stream>>>(ffn_wout, Gall, nullptr,
      96, 255, 9216, 9216L, 2350080L, 0, P, out, nullptr);
}

// Round 9
// 907.791 us; speedup vs baseline: 1.4878x; 1.4878x over previous
//
#include <hip/hip_runtime.h>
#include <hip/hip_bf16.h>
#include <math.h>

using bf16 = __hip_bfloat16;

#define NB 4
#define C_ 96
#define NPIX 36864
#define IMG 9216
#define CH_ST 9216
#define N_ST 884736
#define HID 255
#define EPSF 1e-5f
#define TOT 3538944

// ---------------------------------------------------------------- LayerNorm
// block = 4 channel-quarters x 64 pixels; x cached in 24 regs (single read).
__global__ __launch_bounds__(256) void ln_kernel(const float* __restrict__ X,
                                                 float* __restrict__ Y,
                                                 const float* __restrict__ w,
                                                 const float* __restrict__ b) {
  __shared__ float red[2][4][64];
  __shared__ float wb[192];
  int tid = threadIdx.x;
  if (tid < 192) wb[tid] = (tid < 96) ? w[tid] : b[tid - 96];
  int cq = tid >> 6, px = tid & 63;
  int pix = blockIdx.x * 64 + px;
  int n = pix / IMG, p = pix % IMG;
  const float* xp = X + (long)n * N_ST + (long)(cq * 24) * CH_ST + p;
  float xr[24];
  float s = 0.f, sq = 0.f;
  #pragma unroll
  for (int k = 0; k < 24; k++) {
    float v = xp[(long)k * CH_ST];
    xr[k] = v; s += v; sq += v * v;
  }
  red[0][cq][px] = s; red[1][cq][px] = sq;
  __syncthreads();
  float S  = red[0][0][px] + red[0][1][px] + red[0][2][px] + red[0][3][px];
  float SQ = red[1][0][px] + red[1][1][px] + red[1][2][px] + red[1][3][px];
  float m = S * (1.f / C_);
  float r = rsqrtf(fmaxf(SQ * (1.f / C_) - m * m, 0.f) + EPSF);
  float* yp = Y + (long)n * N_ST + (long)(cq * 24) * CH_ST + p;
  #pragma unroll
  for (int k = 0; k < 24; k++)
    yp[(long)k * CH_ST] = (xr[k] - m) * r * wb[cq * 24 + k] + wb[96 + cq * 24 + k];
}

// ------------------------------------------- transpose NCHW -> [c][n][w][h]
__global__ void trans_kernel(const float* __restrict__ Y0, float* __restrict__ Y0C) {
  __shared__ float T[32][33];
  int nc = blockIdx.z; int n = nc / C_, c = nc % C_;
  int h0 = blockIdx.x * 32, w0 = blockIdx.y * 32;
  int tx = threadIdx.x, ty = threadIdx.y;
  const float* src = Y0 + (long)n * N_ST + (long)c * CH_ST;
  for (int r = 0; r < 4; r++)
    T[ty + 8 * r][tx] = src[(h0 + ty + 8 * r) * 96 + w0 + tx];
  __syncthreads();
  float* dst = Y0C + (long)c * NPIX + (long)n * IMG;
  for (int r = 0; r < 4; r++)
    dst[(w0 + ty + 8 * r) * 96 + h0 + tx] = T[tx][ty + 8 * r];
}

// ---------------------------------------------------------------- generic GEMM
template<int TM, int TN, int EPI>
__global__ __launch_bounds__(256) void gemm_kernel(
    const float* __restrict__ A, const float* __restrict__ B,
    float* __restrict__ Cout, int M, int K, int NperZ,
    long bCstride, long bZstride, int batch,
    const float* __restrict__ X1, float* __restrict__ OutF) {
  constexpr int NT = TN / 16;
  constexpr int RT = TM / 16;
  __shared__ float As[32][TM];
  __shared__ float Bs[32][TN + 4];
  const int tx = threadIdx.x, ty = threadIdx.y;
  const int tid = ty * 16 + tx;
  const int m0 = blockIdx.y * TM;
  const int q0 = blockIdx.x * TN;
  const int z  = blockIdx.z;
  const float* Bz = B + (long)z * bZstride;
  float acc[RT][NT];
  #pragma unroll
  for (int a = 0; a < RT; a++)
    #pragma unroll
    for (int b = 0; b < NT; b++) acc[a][b] = 0.f;

  for (int kk = 0; kk < K; kk += 32) {
    #pragma unroll
    for (int it = 0; it < (32 * TM) / 256; it++) {
      int i = tid + it * 256;
      int c = i / TM, r = i % TM;
      int mm = m0 + r, kc = kk + c;
      As[c][r] = (mm < M && kc < K) ? A[(long)mm * K + kc] : 0.f;
    }
    #pragma unroll
    for (int it = 0; it < (32 * TN) / 256; it++) {
      int i = tid + it * 256;
      int c = i / TN, q = i % TN;
      int kc = kk + c;
      Bs[c][q] = (kc < K) ? Bz[(long)kc * bCstride + q0 + q] : 0.f;
    }
    __syncthreads();
    for (int kc = 0; kc < 32; kc++) {
      float av[RT];
      if constexpr (RT % 4 == 0) {
        #pragma unroll
        for (int u = 0; u < RT / 4; u++) {
          float4 a4 = *(const float4*)&As[kc][ty * RT + 4 * u];
          av[4 * u] = a4.x; av[4 * u + 1] = a4.y; av[4 * u + 2] = a4.z; av[4 * u + 3] = a4.w;
        }
      } else {
        #pragma unroll
        for (int u = 0; u < RT / 2; u++) {
          float2 a2 = *(const float2*)&As[kc][ty * RT + 2 * u];
          av[2 * u] = a2.x; av[2 * u + 1] = a2.y;
        }
      }
      float bv[NT];
      #pragma unroll
      for (int v4 = 0; v4 < NT / 4; v4++) {
        float4 b4 = *(const float4*)&Bs[kc][v4 * 64 + tx * 4];
        bv[v4 * 4] = b4.x; bv[v4 * 4 + 1] = b4.y; bv[v4 * 4 + 2] = b4.z; bv[v4 * 4 + 3] = b4.w;
      }
      #pragma unroll
      for (int a = 0; a < RT; a++)
        #pragma unroll
        for (int b = 0; b < NT; b++)
          acc[a][b] = fmaf(av[a], bv[b], acc[a][b]);
    }
    __syncthreads();
  }
  const long oStride = (long)NperZ * gridDim.z;
  if (EPI == 0) {
    #pragma unroll
    for (int a = 0; a < RT; a++) {
      int mm = m0 + ty * RT + a;
      if (mm < M) {
        float* dst = Cout + (long)mm * oStride + (long)z * NperZ + q0;
        #pragma unroll
        for (int v4 = 0; v4 < NT / 4; v4++)
          *(float4*)(dst + v4 * 64 + tx * 4) =
              make_float4(acc[a][v4 * 4], acc[a][v4 * 4 + 1],
                          acc[a][v4 * 4 + 2], acc[a][v4 * 4 + 3]);
      }
    }
  } else {
    #pragma unroll
    for (int a = 0; a < RT; a++) {
      int mm = m0 + ty * RT + a;
      if (mm < M) {
        #pragma unroll
        for (int v4 = 0; v4 < NT / 4; v4++) {
          int Q = q0 + v4 * 64 + tx * 4;
          int n = batch + z + Q / IMG, p = Q % IMG;
          long base = (long)n * N_ST + (long)mm * CH_ST + p;
          #pragma unroll
          for (int b = 0; b < 4; b++)
            OutF[base + b] = acc[a][v4 * 4 + b] + X1[base + b];
        }
      }
    }
  }
}

// ------------------- per-channel BN stats over a [o][36864] row, 1024 thr
__global__ __launch_bounds__(1024) void rowstat_kernel(const float* __restrict__ D,
                                                       const float* __restrict__ g,
                                                       const float* __restrict__ b,
                                                       float2* __restrict__ aff) {
  int o = blockIdx.x;
  const float4* p = (const float4*)(D + (long)o * NPIX);
  float s = 0.f, sq = 0.f;
  for (int i = threadIdx.x; i < NPIX / 4; i += 1024) {
    float4 v = p[i];
    s  += v.x + v.y + v.z + v.w;
    sq += v.x * v.x + v.y * v.y + v.z * v.z + v.w * v.w;
  }
  for (int off = 32; off; off >>= 1) { s += __shfl_down(s, off); sq += __shfl_down(sq, off); }
  __shared__ float ss[16], ssq[16];
  int wv = threadIdx.x >> 6, lane = threadIdx.x & 63;
  if (lane == 0) { ss[wv] = s; ssq[wv] = sq; }
  __syncthreads();
  if (threadIdx.x == 0) {
    float S = 0.f, SQ = 0.f;
    #pragma unroll
    for (int i = 0; i < 16; i++) { S += ss[i]; SQ += ssq[i]; }
    float m = S / (float)NPIX;
    float var = fmaxf(SQ / (float)NPIX - m * m, 0.f);
    float sc = g[o] * rsqrtf(var + EPSF);
    aff[o] = make_float2(sc, b[o] - m * sc);
  }
}

// ---------------- rel window tables (parallel): block=(side,row), 96 threads
__global__ void relstat_kernel(const float* __restrict__ relp, float* __restrict__ tbl) {
  int i = threadIdx.x;
  if (i >= 96) return;
  int side = blockIdx.x / 27, row = blockIdx.x % 27;
  const float* base = relp + side * 6 * 191;
  float* T = tbl + side * 27 * 96;
  if (row < 6) {
    float s = 0.f;
    for (int d = 0; d < 96; d++) s += base[row * 191 + i + d];
    T[row * 96 + i] = s;
  } else {
    int p = row - 6, c = 0;
    while (p >= 6 - c) { p -= 6 - c; c++; }
    int c2 = c + p;
    float s = 0.f;
    for (int d = 0; d < 96; d++) s += base[c * 191 + i + d] * base[c2 * 191 + i + d];
    T[576 + (row - 6) * 96 + i] = s;
  }
}

// ---------------- algebraic sim stats (Gram identity, no logits)
// NOTE: sqk/sqk2 are BILINEAR per-bb-row (full 96 pixels) -> the ii loop must
// stay inside one warp; splitting ii across blocks drops cross terms (r5 bug).
__global__ __launch_bounds__(256) void simstat2_kernel(const float* __restrict__ QKV,
                                                       const float2* __restrict__ aff,
                                                       const float* __restrict__ tbl,
                                                       float* __restrict__ stats) {
  int g = blockIdx.x & 7, chunk = blockIdx.x >> 3;
  int bbg = threadIdx.x >> 5, lane = threadIdx.x & 31;
  int bb = chunk * 8 + bbg;
  const float* Aq = tbl;
  const float* Wq = tbl + 6 * 96;
  const float* Ak = tbl + 27 * 96;
  const float* Wk = tbl + 27 * 96 + 6 * 96;
  float Sq[6] = {}, Sk[6] = {}, Gq[21] = {}, Gk[21] = {};
  float lq = 0.f, lsq = 0.f, lk = 0.f, lsk = 0.f;
  #pragma unroll
  for (int ii = 0; ii < 3; ii++) {
    int i = lane + 32 * ii;
    float qv[6], kv[6];
    #pragma unroll
    for (int c = 0; c < 6; c++) {
      int oq = g * 24 + c, ok = g * 24 + 6 + c;
      float2 a = aff[oq], b2 = aff[ok];
      qv[c] = QKV[(long)oq * NPIX + bb * 96 + i] * a.x + a.y;
      kv[c] = QKV[(long)ok * NPIX + bb * 96 + i] * b2.x + b2.y;
      Sq[c] += qv[c]; Sk[c] += kv[c];
      lq = fmaf(qv[c], Aq[c * 96 + i], lq);
      lk = fmaf(kv[c], Ak[c * 96 + i], lk);
    }
    int p = 0;
    #pragma unroll
    for (int c = 0; c < 6; c++)
      #pragma unroll
      for (int c2 = c; c2 < 6; c2++, p++) {
        float f = (c == c2) ? 1.f : 2.f;
        float pq = qv[c] * qv[c2], pk = kv[c] * kv[c2];
        Gq[p] += pq; Gk[p] += pk;
        lsq = fmaf(pq * f, Wq[p * 96 + i], lsq);
        lsk = fmaf(pk * f, Wk[p * 96 + i], lsk);
      }
  }
  #pragma unroll
  for (int off = 16; off; off >>= 1) {
    #pragma unroll
    for (int c = 0; c < 6; c++) { Sq[c] += __shfl_down(Sq[c], off, 32); Sk[c] += __shfl_down(Sk[c], off, 32); }
    #pragma unroll
    for (int p = 0; p < 21; p++) { Gq[p] += __shfl_down(Gq[p], off, 32); Gk[p] += __shfl_down(Gk[p], off, 32); }
    lq += __shfl_down(lq, off, 32);  lsq += __shfl_down(lsq, off, 32);
    lk += __shfl_down(lk, off, 32);  lsk += __shfl_down(lsk, off, 32);
  }
  __shared__ float red[6];
  if (threadIdx.x < 6) red[threadIdx.x] = 0.f;
  __syncthreads();
  if (lane == 0) {
    float sqk = 0.f, sqk2 = 0.f;
    #pragma unroll
    for (int c = 0; c < 6; c++) sqk += Sq[c] * Sk[c];
    int p = 0;
    #pragma unroll
    for (int c = 0; c < 6; c++)
      #pragma unroll
      for (int c2 = c; c2 < 6; c2++, p++)
        sqk2 += ((c == c2) ? 1.f : 2.f) * Gq[p] * Gk[p];
    atomicAdd(&red[0], sqk); atomicAdd(&red[3], sqk2);
    atomicAdd(&red[1], lq);  atomicAdd(&red[4], lsq);
    atomicAdd(&red[2], lk);  atomicAdd(&red[5], lsk);
  }
  __syncthreads();
  if (threadIdx.x < 3) {
    atomicAdd(&stats[(threadIdx.x * 8 + g) * 2 + 0], red[threadIdx.x]);
    atomicAdd(&stats[(threadIdx.x * 8 + g) * 2 + 1], red[threadIdx.x + 3]);
  }
}

__global__ void simfin_kernel(const float* __restrict__ stats,
                              const float* __restrict__ gsim,
                              float* __restrict__ scale) {
  int t = threadIdx.x;
  if (t < 24) {
    float cnt = 384.f * 9216.f;
    float m = stats[t * 2] / cnt;
    float var = fmaxf(stats[t * 2 + 1] / cnt - m * m, 0.f);
    scale[t] = gsim[t] * rsqrtf(var + EPSF);
  }
}

// ------------------- attention v5: r7 dataflow (float2 aff, no stat fusion)
// + 4-wave softmax (8 lanes/row) from r8 (correctness-verified there).
__global__ __launch_bounds__(256) void attn_kernel(const float* __restrict__ QKV,
                                                   const float2* __restrict__ aff,
                                                   const float* __restrict__ relp,
                                                   const float* __restrict__ sscale,
                                                   float* __restrict__ OutPre) {
  int blk = blockIdx.x;          // 3072 = 384 bb x 8 g
  int bb = blk >> 3, g = blk & 7;
  __shared__ float qF[6][96];
  __shared__ float kF[6][96];    // raw-affine k (kr term needs it without s0)
  __shared__ float vF[12][96];
  __shared__ float rl[24 * 191]; // rows 0..5 qe*s1, 6..11 ke*s2, 12..23 ve
  __shared__ float P[32][100];   // P[r][96] = rinv
  int tid = threadIdx.x;
  float s0 = sscale[g], s1 = sscale[8 + g], s2 = sscale[16 + g];
  // ---- staging (vectorized, once per (bb,g)) ----
  for (int i = tid; i < 288; i += 256) {         // q (144 quads) then k (144)
    int half = i / 144, r = i % 144;
    int c = r / 24, qd = r % 24;
    int o = g * 24 + half * 6 + c;
    float2 a = aff[o];
    float4 v = *(const float4*)(QKV + (long)o * NPIX + bb * 96 + qd * 4);
    float4 w = make_float4(v.x * a.x + a.y, v.y * a.x + a.y,
                           v.z * a.x + a.y, v.w * a.x + a.y);
    if (half == 0) *(float4*)&qF[c][qd * 4] = w;
    else           *(float4*)&kF[c][qd * 4] = w;
  }
  for (int i = tid; i < 288; i += 256) {         // v (288 quads)
    int c = i / 24, qd = i % 24;
    int o = g * 24 + 12 + c;
    float2 a = aff[o];
    float4 v = *(const float4*)(QKV + (long)o * NPIX + bb * 96 + qd * 4);
    *(float4*)&vF[c][qd * 4] = make_float4(v.x * a.x + a.y, v.y * a.x + a.y,
                                           v.z * a.x + a.y, v.w * a.x + a.y);
  }
  for (int i = tid; i < 1146; i += 256) {        // rl: 24*191 = 4584 words
    int e = i * 4;
    float4 v = *(const float4*)(relp + e);
    float4 w;
    w.x = v.x * ((e + 0) < 1146 ? s1 : (e + 0) < 2292 ? s2 : 1.f);
    w.y = v.y * ((e + 1) < 1146 ? s1 : (e + 1) < 2292 ? s2 : 1.f);
    w.z = v.z * ((e + 2) < 1146 ? s1 : (e + 2) < 2292 ? s2 : 1.f);
    w.w = v.w * ((e + 3) < 1146 ? s1 : (e + 3) < 2292 ? s2 : 1.f);
    *(float4*)&rl[e] = w;
  }
  __syncthreads();
  int hw = tid >> 5, l32 = tid & 31;
  // k-fragment for this thread's phase-1 columns: iq-invariant -> registers.
  float kreg[6][3];
  #pragma unroll
  for (int c = 0; c < 6; c++)
    #pragma unroll
    for (int j = 0; j < 3; j++) kreg[c][j] = kF[c][l32 * 3 + j];
  for (int iq = 0; iq < 3; iq++) {
    int i0 = iq * 32;
    // phase 1: logits; thread tile 4i x 3j (exact cover of 32x96)
    {
      int til = hw * 4;
      int ti = i0 + til;
      int tj = l32 * 3;
      int d0 = ti - tj + 93;
      int e0 = tj - ti + 92;
      float ap[4][3] = {};
      #pragma unroll
      for (int c = 0; c < 6; c++) {
        float4 q4 = *(const float4*)&qF[c][ti];
        float qv[4] = {q4.x, q4.y, q4.z, q4.w};
        float kv0[3], rq[6], rk[6];
        #pragma unroll
        for (int j = 0; j < 3; j++) kv0[j] = s0 * kreg[c][j];
        #pragma unroll
        for (int u = 0; u < 6; u++) { rq[u] = rl[c * 191 + d0 + u]; rk[u] = rl[(6 + c) * 191 + e0 + u]; }
        #pragma unroll
        for (int ii = 0; ii < 4; ii++)
          #pragma unroll
          for (int jj = 0; jj < 3; jj++) {
            ap[ii][jj] = fmaf(qv[ii], kv0[jj], ap[ii][jj]);
            ap[ii][jj] = fmaf(qv[ii], rq[ii - jj + 2], ap[ii][jj]);
            ap[ii][jj] = fmaf(kreg[c][jj], rk[jj - ii + 3], ap[ii][jj]);
          }
      }
      #pragma unroll
      for (int ii = 0; ii < 4; ii++)
        #pragma unroll
        for (int jj = 0; jj < 3; jj++)
          P[til + ii][l32 * 3 + jj] = ap[ii][jj];
    }
    __syncthreads();
    // phase 2: softmax, all 4 waves; row = (tid>>6)*8 + ((tid>>3)&7), 12 cols/lane
    {
      int wv = tid >> 6, rloc = (tid >> 3) & 7, l8 = tid & 7;
      int r = wv * 8 + rloc;
      float* Pr = &P[r][l8 * 12];
      float4 v0 = *(const float4*)(Pr);
      float4 v1 = *(const float4*)(Pr + 4);
      float4 v2 = *(const float4*)(Pr + 8);
      float mx = fmaxf(fmaxf(fmaxf(v0.x, v0.y), fmaxf(v0.z, v0.w)),
                 fmaxf(fmaxf(fmaxf(v1.x, v1.y), fmaxf(v1.z, v1.w)),
                       fmaxf(fmaxf(v2.x, v2.y), fmaxf(v2.z, v2.w))));
      #pragma unroll
      for (int off = 4; off; off >>= 1) mx = fmaxf(mx, __shfl_xor(mx, off, 8));
      v0 = make_float4(__expf(v0.x - mx), __expf(v0.y - mx), __expf(v0.z - mx), __expf(v0.w - mx));
      v1 = make_float4(__expf(v1.x - mx), __expf(v1.y - mx), __expf(v1.z - mx), __expf(v1.w - mx));
      v2 = make_float4(__expf(v2.x - mx), __expf(v2.y - mx), __expf(v2.z - mx), __expf(v2.w - mx));
      float s = v0.x + v0.y + v0.z + v0.w + v1.x + v1.y + v1.z + v1.w
              + v2.x + v2.y + v2.z + v2.w;
      #pragma unroll
      for (int off = 4; off; off >>= 1) s += __shfl_xor(s, off, 8);
      *(float4*)(Pr)     = v0;
      *(float4*)(Pr + 4) = v1;
      *(float4*)(Pr + 8) = v2;
      if (l8 == 0) P[r][96] = 1.f / s;
    }
    __syncthreads();
    // phase 3: warp hw -> out rows orr0..orr0+2; lane -> local i
    {
      int orr0 = hw * 3;
      float acc3[3] = {};
      for (int jq = 0; jq < 24; jq++) {
        int j0 = jq * 4;
        float4 pv = *(const float4*)&P[l32][j0];
        #pragma unroll
        for (int u = 0; u < 3; u++) {
          int orr = orr0 + u, cc = orr >> 1;
          if ((orr & 1) == 0) {
            float4 vv = *(const float4*)&vF[cc][j0];
            acc3[u] += pv.x * vv.x + pv.y * vv.y + pv.z * vv.z + pv.w * vv.w;
          } else {
            const float* rv = &rl[(12 + cc) * 191];
            int bse = (i0 + l32) - j0 + 92;
            float f0 = rv[bse], f1 = rv[bse + 1], f2 = rv[bse + 2], f3 = rv[bse + 3];
            acc3[u] += pv.w * f0 + pv.z * f1 + pv.y * f2 + pv.x * f3;
          }
        }
      }
      float ri = P[l32][96];
      #pragma unroll
      for (int u = 0; u < 3; u++)
        OutPre[(long)(g * 24 + orr0 + u) * NPIX + bb * 96 + i0 + l32] = acc3[u] * ri;
    }
    __syncthreads();
  }
}

// -------- pass1 BN-apply + pair-sum + transpose to NCHW
__global__ void apply1_kernel(const float* __restrict__ OutPre,
                              const float2* __restrict__ aff,
                              float* __restrict__ Y1) {
  __shared__ float T[32][33];
  int z = blockIdx.z; int n = z / C_, cf = z % C_;
  int h0 = blockIdx.x * 32, w0 = blockIdx.y * 32;
  int tx = threadIdx.x, ty = threadIdx.y;
  float2 a0 = aff[2 * cf], a1 = aff[2 * cf + 1];
  const float* r0 = OutPre + (long)(2 * cf) * NPIX + (long)n * IMG;
  const float* r1 = OutPre + (long)(2 * cf + 1) * NPIX + (long)n * IMG;
  for (int r = 0; r < 4; r++) {
    int w = w0 + ty + 8 * r;
    int idx = w * 96 + h0 + tx;
    T[ty + 8 * r][tx] = (r0[idx] * a0.x + a0.y) + (r1[idx] * a1.x + a1.y);
  }
  __syncthreads();
  float* dst = Y1 + (long)n * N_ST + (long)cf * CH_ST;
  for (int r = 0; r < 4; r++)
    dst[(h0 + ty + 8 * r) * 96 + w0 + tx] = T[tx][ty + 8 * r];
}

// -------- pass2 BN-apply + pair-sum + residual with x
__global__ __launch_bounds__(256) void apply2_kernel(const float* __restrict__ OutPre,
                                                     const float2* __restrict__ aff,
                                                     const float* __restrict__ X,
                                                     float* __restrict__ X1out) {
  int idx = blockIdx.x * 256 + threadIdx.x;
  if (idx >= TOT) return;
  int n = idx / N_ST;
  int rem = idx % N_ST;
  int cf = rem / CH_ST;
  int p = rem % CH_ST;
  long off = (long)n * IMG + p;
  float2 a0 = aff[2 * cf], a1 = aff[2 * cf + 1];
  float v = OutPre[(long)(2 * cf) * NPIX + off] * a0.x + a0.y
          + OutPre[(long)(2 * cf + 1) * NPIX + off] * a1.x + a1.y
          + X[idx];
  X1out[idx] = v;
}

// ---------------- depthwise 3x3 SAME + GEGLU, per-batch slice
__global__ __launch_bounds__(256) void dwglu_kernel(const float* __restrict__ H,
                                                    const float* __restrict__ Wdw,
                                                    float* __restrict__ Gout) {
  int idx = blockIdx.x * 256 + threadIdx.x;
  if (idx >= HID * IMG) return;
  int c = idx / IMG;
  int p = idx % IMG, y = p / 96, x = p % 96;
  const float* h1 = H + (long)c * IMG;
  const float* h2 = H + (long)(c + HID) * IMG;
  const float* w1 = Wdw + c * 9;
  const float* w2 = Wdw + (c + HID) * 9;
  float acc1 = 0.f, acc2 = 0.f;
  #pragma unroll
  for (int dy = -1; dy <= 1; dy++) {
    int yy = y + dy; if (yy < 0 || yy >= 96) continue;
    #pragma unroll
    for (int dx = -1; dx <= 1; dx++) {
      int xx = x + dx; if (xx < 0 || xx >= 96) continue;
      int wi = (dy + 1) * 3 + dx + 1;
      acc1 = fmaf(h1[yy * 96 + xx], w1[wi], acc1);
      acc2 = fmaf(h2[yy * 96 + xx], w2[wi], acc2);
    }
  }
  float ge = 0.5f * acc1 * (1.f + erff(acc1 * 0.70710678118654752f));
  Gout[idx] = ge * acc2;
}

// ============================================================== launcher
extern "C" void kernel_launch(void* const* d_in, const int* in_sizes, int n_in,
                              void* d_out, int out_size, void* d_ws, size_t ws_size,
                              hipStream_t stream) {
  const float* x       = (const float*)d_in[0];
  const float* ln1w    = (const float*)d_in[1];
  const float* ln1b    = (const float*)d_in[2];
  const float* h_wqkv  = (const float*)d_in[3];
  const float* h_gqkv  = (const float*)d_in[4];
  const float* h_bqkv  = (const float*)d_in[5];
  const float* h_rel   = (const float*)d_in[6];
  const float* h_gsim  = (const float*)d_in[7];
  const float* h_gout  = (const float*)d_in[9];
  const float* h_bout  = (const float*)d_in[10];
  const float* w_wqkv  = (const float*)d_in[11];
  const float* w_gqkv  = (const float*)d_in[12];
  const float* w_bqkv  = (const float*)d_in[13];
  const float* w_rel   = (const float*)d_in[14];
  const float* w_gsim  = (const float*)d_in[15];
  const float* w_gout  = (const float*)d_in[17];
  const float* w_bout  = (const float*)d_in[18];
  const float* ln2w    = (const float*)d_in[19];
  const float* ln2b    = (const float*)d_in[20];
  const float* ffn_win = (const float*)d_in[21];
  const float* ffn_wdw = (const float*)d_in[22];
  const float* ffn_wout= (const float*)d_in[23];
  float* out = (float*)d_out;

  float* ws = (float*)d_ws;
  float* P = ws;
  float* Q = ws + 3538944;
  float* R = ws + 7077888;
  float* S = ws + 14155776;
  float* Gall = R;
  float* Hbuf = ws + 16478208;
  float* stats = ws + 21233664;
  const size_t need_bytes = (21233664ull + 8192ull) * 4ull;
  if (ws_size < need_bytes) return;

  float2* qkv_aff = (float2*)stats;
  float2* out_aff = (float2*)(stats + 384);
  float*  sim_st  = stats + 768;
  float*  sim_sc  = stats + 864;
  float*  tbl     = stats + 1024;

  hipMemsetAsync(sim_st, 0, 96 * sizeof(float), stream);

  dim3 b256(256), b1616(16, 16), b328(32, 8);

  ln_kernel<<<576, b256, 0, stream>>>(x, P, ln1w, ln1b);
  trans_kernel<<<dim3(3, 3, 384), b328, 0, stream>>>(P, Q);

  // ---- pass 1 (attention along H) ----
  gemm_kernel<96, 128, 0><<<dim3(288, 2, 1), b1616, 0, stream>>>(h_wqkv, Q, R,
      192, 96, 36864, 36864L, 0L, 0, nullptr, nullptr);
  rowstat_kernel<<<192, 1024, 0, stream>>>(R, h_gqkv, h_bqkv, qkv_aff);
  relstat_kernel<<<54, 96, 0, stream>>>(h_rel, tbl);
  simstat2_kernel<<<384, b256, 0, stream>>>(R, qkv_aff, tbl, sim_st);
  simfin_kernel<<<1, 32, 0, stream>>>(sim_st, h_gsim, sim_sc);
  attn_kernel<<<3072, b256, 0, stream>>>(R, qkv_aff, h_rel, sim_sc, S);
  rowstat_kernel<<<192, 1024, 0, stream>>>(S, h_gout, h_bout, out_aff);
  apply1_kernel<<<dim3(3, 3, 384), b328, 0, stream>>>(S, out_aff, P);

  // ---- pass 2 (attention along W) ----
  gemm_kernel<96, 128, 0><<<dim3(72, 2, 4), b1616, 0, stream>>>(w_wqkv, P, R,
      192, 96, 9216, 9216L, 884736L, 0, nullptr, nullptr);
  rowstat_kernel<<<192, 1024, 0, stream>>>(R, w_gqkv, w_bqkv, qkv_aff);
  relstat_kernel<<<54, 96, 0, stream>>>(w_rel, tbl);
  simstat2_kernel<<<384, b256, 0, stream>>>(R, qkv_aff, tbl, sim_st + 48);
  simfin_kernel<<<1, 32, 0, stream>>>(sim_st + 48, w_gsim, sim_sc + 24);
  attn_kernel<<<3072, b256, 0, stream>>>(R, qkv_aff, w_rel, sim_sc + 24, S);
  rowstat_kernel<<<192, 1024, 0, stream>>>(S, w_gout, w_bout, out_aff);
  apply2_kernel<<<13824, b256, 0, stream>>>(S, out_aff, x, P);

  // ---- FFN ----
  ln_kernel<<<576, b256, 0, stream>>>(P, Q, ln2w, ln2b);
  for (int n = 0; n < NB; n++) {
    gemm_kernel<128, 64, 0><<<dim3(144, 4, 1), b1616, 0, stream>>>(ffn_win, Q + (long)n * N_ST, Hbuf,
        510, 96, 9216, 9216L, 0L, 0, nullptr, nullptr);
    dwglu_kernel<<<9180, b256, 0, stream>>>(Hbuf, ffn_wdw, Gall + (long)n * 2350080);
  }
  gemm_kernel<96, 64, 1><<<dim3(144, 1, 4), b1616, 0, stream>>>(ffn_wout, Gall, nullptr,
      96, 255, 9216, 9216L, 2350080L, 0, P, out);
}

// Round 13
// 846.008 us; speedup vs baseline: 1.5965x; 1.0730x over previous
//
#include <hip/hip_runtime.h>
#include <hip/hip_bf16.h>
#include <math.h>

using bf16 = __hip_bfloat16;

#define NB 4
#define C_ 96
#define NPIX 36864
#define IMG 9216
#define CH_ST 9216
#define N_ST 884736
#define HID 255
#define EPSF 1e-5f
#define TOT 3538944

// ---------------------------------------------------------------- LayerNorm
// block = 4 channel-quarters x 64 pixels; x cached in 24 regs (single read).
__global__ __launch_bounds__(256) void ln_kernel(const float* __restrict__ X,
                                                 float* __restrict__ Y,
                                                 const float* __restrict__ w,
                                                 const float* __restrict__ b) {
  __shared__ float red[2][4][64];
  __shared__ float wb[192];
  int tid = threadIdx.x;
  if (tid < 192) wb[tid] = (tid < 96) ? w[tid] : b[tid - 96];
  int cq = tid >> 6, px = tid & 63;
  int pix = blockIdx.x * 64 + px;
  int n = pix / IMG, p = pix % IMG;
  const float* xp = X + (long)n * N_ST + (long)(cq * 24) * CH_ST + p;
  float xr[24];
  float s = 0.f, sq = 0.f;
  #pragma unroll
  for (int k = 0; k < 24; k++) {
    float v = xp[(long)k * CH_ST];
    xr[k] = v; s += v; sq += v * v;
  }
  red[0][cq][px] = s; red[1][cq][px] = sq;
  __syncthreads();
  float S  = red[0][0][px] + red[0][1][px] + red[0][2][px] + red[0][3][px];
  float SQ = red[1][0][px] + red[1][1][px] + red[1][2][px] + red[1][3][px];
  float m = S * (1.f / C_);
  float r = rsqrtf(fmaxf(SQ * (1.f / C_) - m * m, 0.f) + EPSF);
  float* yp = Y + (long)n * N_ST + (long)(cq * 24) * CH_ST + p;
  #pragma unroll
  for (int k = 0; k < 24; k++)
    yp[(long)k * CH_ST] = (xr[k] - m) * r * wb[cq * 24 + k] + wb[96 + cq * 24 + k];
}

// ------------------------------------------- transpose NCHW -> [c][n][w][h]
__global__ void trans_kernel(const float* __restrict__ Y0, float* __restrict__ Y0C) {
  __shared__ float T[32][33];
  int nc = blockIdx.z; int n = nc / C_, c = nc % C_;
  int h0 = blockIdx.x * 32, w0 = blockIdx.y * 32;
  int tx = threadIdx.x, ty = threadIdx.y;
  const float* src = Y0 + (long)n * N_ST + (long)c * CH_ST;
  for (int r = 0; r < 4; r++)
    T[ty + 8 * r][tx] = src[(h0 + ty + 8 * r) * 96 + w0 + tx];
  __syncthreads();
  float* dst = Y0C + (long)c * NPIX + (long)n * IMG;
  for (int r = 0; r < 4; r++)
    dst[(w0 + ty + 8 * r) * 96 + h0 + tx] = T[tx][ty + 8 * r];
}

// ---------------------------------------------------------------- generic GEMM
template<int TM, int TN, int EPI>
__global__ __launch_bounds__(256) void gemm_kernel(
    const float* __restrict__ A, const float* __restrict__ B,
    float* __restrict__ Cout, int M, int K, int NperZ,
    long bCstride, long bZstride, int batch,
    const float* __restrict__ X1, float* __restrict__ OutF) {
  constexpr int NT = TN / 16;
  constexpr int RT = TM / 16;
  __shared__ float As[32][TM];
  __shared__ float Bs[32][TN + 4];
  const int tx = threadIdx.x, ty = threadIdx.y;
  const int tid = ty * 16 + tx;
  const int m0 = blockIdx.y * TM;
  const int q0 = blockIdx.x * TN;
  const int z  = blockIdx.z;
  const float* Bz = B + (long)z * bZstride;
  float acc[RT][NT];
  #pragma unroll
  for (int a = 0; a < RT; a++)
    #pragma unroll
    for (int b = 0; b < NT; b++) acc[a][b] = 0.f;

  for (int kk = 0; kk < K; kk += 32) {
    #pragma unroll
    for (int it = 0; it < (32 * TM) / 256; it++) {
      int i = tid + it * 256;
      int c = i / TM, r = i % TM;
      int mm = m0 + r, kc = kk + c;
      As[c][r] = (mm < M && kc < K) ? A[(long)mm * K + kc] : 0.f;
    }
    #pragma unroll
    for (int it = 0; it < (32 * TN) / 256; it++) {
      int i = tid + it * 256;
      int c = i / TN, q = i % TN;
      int kc = kk + c;
      Bs[c][q] = (kc < K) ? Bz[(long)kc * bCstride + q0 + q] : 0.f;
    }
    __syncthreads();
    for (int kc = 0; kc < 32; kc++) {
      float av[RT];
      if constexpr (RT % 4 == 0) {
        #pragma unroll
        for (int u = 0; u < RT / 4; u++) {
          float4 a4 = *(const float4*)&As[kc][ty * RT + 4 * u];
          av[4 * u] = a4.x; av[4 * u + 1] = a4.y; av[4 * u + 2] = a4.z; av[4 * u + 3] = a4.w;
        }
      } else {
        #pragma unroll
        for (int u = 0; u < RT / 2; u++) {
          float2 a2 = *(const float2*)&As[kc][ty * RT + 2 * u];
          av[2 * u] = a2.x; av[2 * u + 1] = a2.y;
        }
      }
      float bv[NT];
      #pragma unroll
      for (int v4 = 0; v4 < NT / 4; v4++) {
        float4 b4 = *(const float4*)&Bs[kc][v4 * 64 + tx * 4];
        bv[v4 * 4] = b4.x; bv[v4 * 4 + 1] = b4.y; bv[v4 * 4 + 2] = b4.z; bv[v4 * 4 + 3] = b4.w;
      }
      #pragma unroll
      for (int a = 0; a < RT; a++)
        #pragma unroll
        for (int b = 0; b < NT; b++)
          acc[a][b] = fmaf(av[a], bv[b], acc[a][b]);
    }
    __syncthreads();
  }
  const long oStride = (long)NperZ * gridDim.z;
  if (EPI == 0) {
    #pragma unroll
    for (int a = 0; a < RT; a++) {
      int mm = m0 + ty * RT + a;
      if (mm < M) {
        float* dst = Cout + (long)mm * oStride + (long)z * NperZ + q0;
        #pragma unroll
        for (int v4 = 0; v4 < NT / 4; v4++)
          *(float4*)(dst + v4 * 64 + tx * 4) =
              make_float4(acc[a][v4 * 4], acc[a][v4 * 4 + 1],
                          acc[a][v4 * 4 + 2], acc[a][v4 * 4 + 3]);
      }
    }
  } else {
    #pragma unroll
    for (int a = 0; a < RT; a++) {
      int mm = m0 + ty * RT + a;
      if (mm < M) {
        #pragma unroll
        for (int v4 = 0; v4 < NT / 4; v4++) {
          int Q = q0 + v4 * 64 + tx * 4;
          int n = batch + z + Q / IMG, p = Q % IMG;
          long base = (long)n * N_ST + (long)mm * CH_ST + p;
          #pragma unroll
          for (int b = 0; b < 4; b++)
            OutF[base + b] = acc[a][v4 * 4 + b] + X1[base + b];
        }
      }
    }
  }
}

// ------------------- per-channel BN stats over a [o][36864] row, 1024 thr
__global__ __launch_bounds__(1024) void rowstat_kernel(const float* __restrict__ D,
                                                       const float* __restrict__ g,
                                                       const float* __restrict__ b,
                                                       float2* __restrict__ aff) {
  int o = blockIdx.x;
  const float4* p = (const float4*)(D + (long)o * NPIX);
  float s = 0.f, sq = 0.f;
  for (int i = threadIdx.x; i < NPIX / 4; i += 1024) {
    float4 v = p[i];
    s  += v.x + v.y + v.z + v.w;
    sq += v.x * v.x + v.y * v.y + v.z * v.z + v.w * v.w;
  }
  for (int off = 32; off; off >>= 1) { s += __shfl_down(s, off); sq += __shfl_down(sq, off); }
  __shared__ float ss[16], ssq[16];
  int wv = threadIdx.x >> 6, lane = threadIdx.x & 63;
  if (lane == 0) { ss[wv] = s; ssq[wv] = sq; }
  __syncthreads();
  if (threadIdx.x == 0) {
    float S = 0.f, SQ = 0.f;
    #pragma unroll
    for (int i = 0; i < 16; i++) { S += ss[i]; SQ += ssq[i]; }
    float m = S / (float)NPIX;
    float var = fmaxf(SQ / (float)NPIX - m * m, 0.f);
    float sc = g[o] * rsqrtf(var + EPSF);
    aff[o] = make_float2(sc, b[o] - m * sc);
  }
}

// ---------------- rel window tables (parallel): block=(side,row), 96 threads
__global__ void relstat_kernel(const float* __restrict__ relp, float* __restrict__ tbl) {
  int i = threadIdx.x;
  if (i >= 96) return;
  int side = blockIdx.x / 27, row = blockIdx.x % 27;
  const float* base = relp + side * 6 * 191;
  float* T = tbl + side * 27 * 96;
  if (row < 6) {
    float s = 0.f;
    for (int d = 0; d < 96; d++) s += base[row * 191 + i + d];
    T[row * 96 + i] = s;
  } else {
    int p = row - 6, c = 0;
    while (p >= 6 - c) { p -= 6 - c; c++; }
    int c2 = c + p;
    float s = 0.f;
    for (int d = 0; d < 96; d++) s += base[c * 191 + i + d] * base[c2 * 191 + i + d];
    T[576 + (row - 6) * 96 + i] = s;
  }
}

// ---------------- algebraic sim stats (Gram identity, no logits)
// NOTE: sqk/sqk2 are BILINEAR per-bb-row (full 96 pixels) -> the ii loop must
// stay inside one warp; splitting ii across blocks drops cross terms (r5 bug).
__global__ __launch_bounds__(256) void simstat2_kernel(const float* __restrict__ QKV,
                                                       const float2* __restrict__ aff,
                                                       const float* __restrict__ tbl,
                                                       float* __restrict__ stats) {
  int g = blockIdx.x & 7, chunk = blockIdx.x >> 3;
  int bbg = threadIdx.x >> 5, lane = threadIdx.x & 31;
  int bb = chunk * 8 + bbg;
  const float* Aq = tbl;
  const float* Wq = tbl + 6 * 96;
  const float* Ak = tbl + 27 * 96;
  const float* Wk = tbl + 27 * 96 + 6 * 96;
  float Sq[6] = {}, Sk[6] = {}, Gq[21] = {}, Gk[21] = {};
  float lq = 0.f, lsq = 0.f, lk = 0.f, lsk = 0.f;
  #pragma unroll
  for (int ii = 0; ii < 3; ii++) {
    int i = lane + 32 * ii;
    float qv[6], kv[6];
    #pragma unroll
    for (int c = 0; c < 6; c++) {
      int oq = g * 24 + c, ok = g * 24 + 6 + c;
      float2 a = aff[oq], b2 = aff[ok];
      qv[c] = QKV[(long)oq * NPIX + bb * 96 + i] * a.x + a.y;
      kv[c] = QKV[(long)ok * NPIX + bb * 96 + i] * b2.x + b2.y;
      Sq[c] += qv[c]; Sk[c] += kv[c];
      lq = fmaf(qv[c], Aq[c * 96 + i], lq);
      lk = fmaf(kv[c], Ak[c * 96 + i], lk);
    }
    int p = 0;
    #pragma unroll
    for (int c = 0; c < 6; c++)
      #pragma unroll
      for (int c2 = c; c2 < 6; c2++, p++) {
        float f = (c == c2) ? 1.f : 2.f;
        float pq = qv[c] * qv[c2], pk = kv[c] * kv[c2];
        Gq[p] += pq; Gk[p] += pk;
        lsq = fmaf(pq * f, Wq[p * 96 + i], lsq);
        lsk = fmaf(pk * f, Wk[p * 96 + i], lsk);
      }
  }
  #pragma unroll
  for (int off = 16; off; off >>= 1) {
    #pragma unroll
    for (int c = 0; c < 6; c++) { Sq[c] += __shfl_down(Sq[c], off, 32); Sk[c] += __shfl_down(Sk[c], off, 32); }
    #pragma unroll
    for (int p = 0; p < 21; p++) { Gq[p] += __shfl_down(Gq[p], off, 32); Gk[p] += __shfl_down(Gk[p], off, 32); }
    lq += __shfl_down(lq, off, 32);  lsq += __shfl_down(lsq, off, 32);
    lk += __shfl_down(lk, off, 32);  lsk += __shfl_down(lsk, off, 32);
  }
  __shared__ float red[6];
  if (threadIdx.x < 6) red[threadIdx.x] = 0.f;
  __syncthreads();
  if (lane == 0) {
    float sqk = 0.f, sqk2 = 0.f;
    #pragma unroll
    for (int c = 0; c < 6; c++) sqk += Sq[c] * Sk[c];
    int p = 0;
    #pragma unroll
    for (int c = 0; c < 6; c++)
      #pragma unroll
      for (int c2 = c; c2 < 6; c2++, p++)
        sqk2 += ((c == c2) ? 1.f : 2.f) * Gq[p] * Gk[p];
    atomicAdd(&red[0], sqk); atomicAdd(&red[3], sqk2);
    atomicAdd(&red[1], lq);  atomicAdd(&red[4], lsq);
    atomicAdd(&red[2], lk);  atomicAdd(&red[5], lsk);
  }
  __syncthreads();
  if (threadIdx.x < 3) {
    atomicAdd(&stats[(threadIdx.x * 8 + g) * 2 + 0], red[threadIdx.x]);
    atomicAdd(&stats[(threadIdx.x * 8 + g) * 2 + 1], red[threadIdx.x + 3]);
  }
}

__global__ void simfin_kernel(const float* __restrict__ stats,
                              const float* __restrict__ gsim,
                              float* __restrict__ scale) {
  int t = threadIdx.x;
  if (t < 24) {
    float cnt = 384.f * 9216.f;
    float m = stats[t * 2] / cnt;
    float var = fmaxf(stats[t * 2 + 1] / cnt - m * m, 0.f);
    scale[t] = gsim[t] * rsqrtf(var + EPSF);
  }
}

// ------------------- attention v5 (r9-verified): float2 aff, k-hoist,
// 4-wave softmax (8 lanes/row).
__global__ __launch_bounds__(256) void attn_kernel(const float* __restrict__ QKV,
                                                   const float2* __restrict__ aff,
                                                   const float* __restrict__ relp,
                                                   const float* __restrict__ sscale,
                                                   float* __restrict__ OutPre) {
  int blk = blockIdx.x;          // 3072 = 384 bb x 8 g
  int bb = blk >> 3, g = blk & 7;
  __shared__ float qF[6][96];
  __shared__ float kF[6][96];    // raw-affine k (kr term needs it without s0)
  __shared__ float vF[12][96];
  __shared__ float rl[24 * 191]; // rows 0..5 qe*s1, 6..11 ke*s2, 12..23 ve
  __shared__ float P[32][100];   // P[r][96] = rinv
  int tid = threadIdx.x;
  float s0 = sscale[g], s1 = sscale[8 + g], s2 = sscale[16 + g];
  // ---- staging (vectorized, once per (bb,g)) ----
  for (int i = tid; i < 288; i += 256) {         // q (144 quads) then k (144)
    int half = i / 144, r = i % 144;
    int c = r / 24, qd = r % 24;
    int o = g * 24 + half * 6 + c;
    float2 a = aff[o];
    float4 v = *(const float4*)(QKV + (long)o * NPIX + bb * 96 + qd * 4);
    float4 w = make_float4(v.x * a.x + a.y, v.y * a.x + a.y,
                           v.z * a.x + a.y, v.w * a.x + a.y);
    if (half == 0) *(float4*)&qF[c][qd * 4] = w;
    else           *(float4*)&kF[c][qd * 4] = w;
  }
  for (int i = tid; i < 288; i += 256) {         // v (288 quads)
    int c = i / 24, qd = i % 24;
    int o = g * 24 + 12 + c;
    float2 a = aff[o];
    float4 v = *(const float4*)(QKV + (long)o * NPIX + bb * 96 + qd * 4);
    *(float4*)&vF[c][qd * 4] = make_float4(v.x * a.x + a.y, v.y * a.x + a.y,
                                           v.z * a.x + a.y, v.w * a.x + a.y);
  }
  for (int i = tid; i < 1146; i += 256) {        // rl: 24*191 = 4584 words
    int e = i * 4;
    float4 v = *(const float4*)(relp + e);
    float4 w;
    w.x = v.x * ((e + 0) < 1146 ? s1 : (e + 0) < 2292 ? s2 : 1.f);
    w.y = v.y * ((e + 1) < 1146 ? s1 : (e + 1) < 2292 ? s2 : 1.f);
    w.z = v.z * ((e + 2) < 1146 ? s1 : (e + 2) < 2292 ? s2 : 1.f);
    w.w = v.w * ((e + 3) < 1146 ? s1 : (e + 3) < 2292 ? s2 : 1.f);
    *(float4*)&rl[e] = w;
  }
  __syncthreads();
  int hw = tid >> 5, l32 = tid & 31;
  // k-fragment for this thread's phase-1 columns: iq-invariant -> registers.
  float kreg[6][3];
  #pragma unroll
  for (int c = 0; c < 6; c++)
    #pragma unroll
    for (int j = 0; j < 3; j++) kreg[c][j] = kF[c][l32 * 3 + j];
  for (int iq = 0; iq < 3; iq++) {
    int i0 = iq * 32;
    // phase 1: logits; thread tile 4i x 3j (exact cover of 32x96)
    {
      int til = hw * 4;
      int ti = i0 + til;
      int tj = l32 * 3;
      int d0 = ti - tj + 93;
      int e0 = tj - ti + 92;
      float ap[4][3] = {};
      #pragma unroll
      for (int c = 0; c < 6; c++) {
        float4 q4 = *(const float4*)&qF[c][ti];
        float qv[4] = {q4.x, q4.y, q4.z, q4.w};
        float kv0[3], rq[6], rk[6];
        #pragma unroll
        for (int j = 0; j < 3; j++) kv0[j] = s0 * kreg[c][j];
        #pragma unroll
        for (int u = 0; u < 6; u++) { rq[u] = rl[c * 191 + d0 + u]; rk[u] = rl[(6 + c) * 191 + e0 + u]; }
        #pragma unroll
        for (int ii = 0; ii < 4; ii++)
          #pragma unroll
          for (int jj = 0; jj < 3; jj++) {
            ap[ii][jj] = fmaf(qv[ii], kv0[jj], ap[ii][jj]);
            ap[ii][jj] = fmaf(qv[ii], rq[ii - jj + 2], ap[ii][jj]);
            ap[ii][jj] = fmaf(kreg[c][jj], rk[jj - ii + 3], ap[ii][jj]);
          }
      }
      #pragma unroll
      for (int ii = 0; ii < 4; ii++)
        #pragma unroll
        for (int jj = 0; jj < 3; jj++)
          P[til + ii][l32 * 3 + jj] = ap[ii][jj];
    }
    __syncthreads();
    // phase 2: softmax, all 4 waves; row = (tid>>6)*8 + ((tid>>3)&7), 12 cols/lane
    {
      int wv = tid >> 6, rloc = (tid >> 3) & 7, l8 = tid & 7;
      int r = wv * 8 + rloc;
      float* Pr = &P[r][l8 * 12];
      float4 v0 = *(const float4*)(Pr);
      float4 v1 = *(const float4*)(Pr + 4);
      float4 v2 = *(const float4*)(Pr + 8);
      float mx = fmaxf(fmaxf(fmaxf(v0.x, v0.y), fmaxf(v0.z, v0.w)),
                 fmaxf(fmaxf(fmaxf(v1.x, v1.y), fmaxf(v1.z, v1.w)),
                       fmaxf(fmaxf(v2.x, v2.y), fmaxf(v2.z, v2.w))));
      #pragma unroll
      for (int off = 4; off; off >>= 1) mx = fmaxf(mx, __shfl_xor(mx, off, 8));
      v0 = make_float4(__expf(v0.x - mx), __expf(v0.y - mx), __expf(v0.z - mx), __expf(v0.w - mx));
      v1 = make_float4(__expf(v1.x - mx), __expf(v1.y - mx), __expf(v1.z - mx), __expf(v1.w - mx));
      v2 = make_float4(__expf(v2.x - mx), __expf(v2.y - mx), __expf(v2.z - mx), __expf(v2.w - mx));
      float s = v0.x + v0.y + v0.z + v0.w + v1.x + v1.y + v1.z + v1.w
              + v2.x + v2.y + v2.z + v2.w;
      #pragma unroll
      for (int off = 4; off; off >>= 1) s += __shfl_xor(s, off, 8);
      *(float4*)(Pr)     = v0;
      *(float4*)(Pr + 4) = v1;
      *(float4*)(Pr + 8) = v2;
      if (l8 == 0) P[r][96] = 1.f / s;
    }
    __syncthreads();
    // phase 3: warp hw -> out rows orr0..orr0+2; lane -> local i
    {
      int orr0 = hw * 3;
      float acc3[3] = {};
      for (int jq = 0; jq < 24; jq++) {
        int j0 = jq * 4;
        float4 pv = *(const float4*)&P[l32][j0];
        #pragma unroll
        for (int u = 0; u < 3; u++) {
          int orr = orr0 + u, cc = orr >> 1;
          if ((orr & 1) == 0) {
            float4 vv = *(const float4*)&vF[cc][j0];
            acc3[u] += pv.x * vv.x + pv.y * vv.y + pv.z * vv.z + pv.w * vv.w;
          } else {
            const float* rv = &rl[(12 + cc) * 191];
            int bse = (i0 + l32) - j0 + 92;
            float f0 = rv[bse], f1 = rv[bse + 1], f2 = rv[bse + 2], f3 = rv[bse + 3];
            acc3[u] += pv.w * f0 + pv.z * f1 + pv.y * f2 + pv.x * f3;
          }
        }
      }
      float ri = P[l32][96];
      #pragma unroll
      for (int u = 0; u < 3; u++)
        OutPre[(long)(g * 24 + orr0 + u) * NPIX + bb * 96 + i0 + l32] = acc3[u] * ri;
    }
    __syncthreads();
  }
}

// -------- pass1 BN-apply + pair-sum + transpose to NCHW
__global__ void apply1_kernel(const float* __restrict__ OutPre,
                              const float2* __restrict__ aff,
                              float* __restrict__ Y1) {
  __shared__ float T[32][33];
  int z = blockIdx.z; int n = z / C_, cf = z % C_;
  int h0 = blockIdx.x * 32, w0 = blockIdx.y * 32;
  int tx = threadIdx.x, ty = threadIdx.y;
  float2 a0 = aff[2 * cf], a1 = aff[2 * cf + 1];
  const float* r0 = OutPre + (long)(2 * cf) * NPIX + (long)n * IMG;
  const float* r1 = OutPre + (long)(2 * cf + 1) * NPIX + (long)n * IMG;
  for (int r = 0; r < 4; r++) {
    int w = w0 + ty + 8 * r;
    int idx = w * 96 + h0 + tx;
    T[ty + 8 * r][tx] = (r0[idx] * a0.x + a0.y) + (r1[idx] * a1.x + a1.y);
  }
  __syncthreads();
  float* dst = Y1 + (long)n * N_ST + (long)cf * CH_ST;
  for (int r = 0; r < 4; r++)
    dst[(h0 + ty + 8 * r) * 96 + w0 + tx] = T[tx][ty + 8 * r];
}

// -------- fused pass2 BN-apply + residual + LayerNorm2 (ln-v3 pattern).
// Writes X1 (for ffn_out residual) and ln2 output; same-thread reuse only.
__global__ __launch_bounds__(256) void apl2_kernel(const float* __restrict__ OutPre,
                                                   const float2* __restrict__ aff,
                                                   const float* __restrict__ X,
                                                   const float* __restrict__ w,
                                                   const float* __restrict__ b,
                                                   float* __restrict__ X1out,
                                                   float* __restrict__ Yln) {
  __shared__ float red[2][4][64];
  __shared__ float2 affs[192];
  __shared__ float wb[192];
  int tid = threadIdx.x;
  if (tid < 192) { affs[tid] = aff[tid]; wb[tid] = (tid < 96) ? w[tid] : b[tid - 96]; }
  __syncthreads();
  int cq = tid >> 6, px = tid & 63;
  int pix = blockIdx.x * 64 + px;
  int n = pix / IMG, p = pix % IMG;
  const float* o0p = OutPre + (long)n * IMG + p;
  const float* xp = X + (long)n * N_ST + (long)(cq * 24) * CH_ST + p;
  float vr[24];
  float s = 0.f, sq = 0.f;
  #pragma unroll
  for (int k = 0; k < 24; k++) {
    int c = cq * 24 + k;
    float2 a0 = affs[2 * c], a1 = affs[2 * c + 1];
    float o0 = o0p[(long)(2 * c) * NPIX];
    float o1 = o0p[(long)(2 * c + 1) * NPIX];
    float v = o0 * a0.x + a0.y + o1 * a1.x + a1.y + xp[(long)k * CH_ST];
    vr[k] = v; s += v; sq += v * v;
  }
  red[0][cq][px] = s; red[1][cq][px] = sq;
  __syncthreads();
  float S  = red[0][0][px] + red[0][1][px] + red[0][2][px] + red[0][3][px];
  float SQ = red[1][0][px] + red[1][1][px] + red[1][2][px] + red[1][3][px];
  float m = S * (1.f / C_);
  float r = rsqrtf(fmaxf(SQ * (1.f / C_) - m * m, 0.f) + EPSF);
  float* x1p = X1out + (long)n * N_ST + (long)(cq * 24) * CH_ST + p;
  float* yp  = Yln   + (long)n * N_ST + (long)(cq * 24) * CH_ST + p;
  #pragma unroll
  for (int k = 0; k < 24; k++) {
    x1p[(long)k * CH_ST] = vr[k];
    int c = cq * 24 + k;
    yp[(long)k * CH_ST] = (vr[k] - m) * r * wb[c] + wb[96 + c];
  }
}

// ---------------- depthwise 3x3 SAME + GEGLU, per-batch slice (fallback)
__global__ __launch_bounds__(256) void dwglu_kernel(const float* __restrict__ H,
                                                    const float* __restrict__ Wdw,
                                                    float* __restrict__ Gout) {
  int idx = blockIdx.x * 256 + threadIdx.x;
  if (idx >= HID * IMG) return;
  int c = idx / IMG;
  int p = idx % IMG, y = p / 96, x = p % 96;
  const float* h1 = H + (long)c * IMG;
  const float* h2 = H + (long)(c + HID) * IMG;
  const float* w1 = Wdw + c * 9;
  const float* w2 = Wdw + (c + HID) * 9;
  float acc1 = 0.f, acc2 = 0.f;
  #pragma unroll
  for (int dy = -1; dy <= 1; dy++) {
    int yy = y + dy; if (yy < 0 || yy >= 96) continue;
    #pragma unroll
    for (int dx = -1; dx <= 1; dx++) {
      int xx = x + dx; if (xx < 0 || xx >= 96) continue;
      int wi = (dy + 1) * 3 + dx + 1;
      acc1 = fmaf(h1[yy * 96 + xx], w1[wi], acc1);
      acc2 = fmaf(h2[yy * 96 + xx], w2[wi], acc2);
    }
  }
  float ge = 0.5f * acc1 * (1.f + erff(acc1 * 0.70710678118654752f));
  Gout[idx] = ge * acc2;
}

// ---------------- batched depthwise 3x3 + GEGLU: H layout [c][n][p] (z=4 gemm)
__global__ __launch_bounds__(256) void dwglu4_kernel(const float* __restrict__ H,
                                                     const float* __restrict__ Wdw,
                                                     float* __restrict__ Gout) {
  int idx = blockIdx.x * 256 + threadIdx.x;
  if (idx >= HID * IMG * NB) return;
  int c = idx / (IMG * NB);
  int rem = idx % (IMG * NB);
  int nb = rem / IMG;
  int p = rem % IMG, y = p / 96, x = p % 96;
  const float* h1 = H + (long)c * (IMG * NB) + (long)nb * IMG;
  const float* h2 = H + (long)(c + HID) * (IMG * NB) + (long)nb * IMG;
  const float* w1 = Wdw + c * 9;
  const float* w2 = Wdw + (c + HID) * 9;
  float acc1 = 0.f, acc2 = 0.f;
  #pragma unroll
  for (int dy = -1; dy <= 1; dy++) {
    int yy = y + dy; if (yy < 0 || yy >= 96) continue;
    #pragma unroll
    for (int dx = -1; dx <= 1; dx++) {
      int xx = x + dx; if (xx < 0 || xx >= 96) continue;
      int wi = (dy + 1) * 3 + dx + 1;
      acc1 = fmaf(h1[yy * 96 + xx], w1[wi], acc1);
      acc2 = fmaf(h2[yy * 96 + xx], w2[wi], acc2);
    }
  }
  float ge = 0.5f * acc1 * (1.f + erff(acc1 * 0.70710678118654752f));
  Gout[(long)nb * 2350080 + (long)c * IMG + p] = ge * acc2;
}

// ============================================================== launcher
extern "C" void kernel_launch(void* const* d_in, const int* in_sizes, int n_in,
                              void* d_out, int out_size, void* d_ws, size_t ws_size,
                              hipStream_t stream) {
  const float* x       = (const float*)d_in[0];
  const float* ln1w    = (const float*)d_in[1];
  const float* ln1b    = (const float*)d_in[2];
  const float* h_wqkv  = (const float*)d_in[3];
  const float* h_gqkv  = (const float*)d_in[4];
  const float* h_bqkv  = (const float*)d_in[5];
  const float* h_rel   = (const float*)d_in[6];
  const float* h_gsim  = (const float*)d_in[7];
  const float* h_gout  = (const float*)d_in[9];
  const float* h_bout  = (const float*)d_in[10];
  const float* w_wqkv  = (const float*)d_in[11];
  const float* w_gqkv  = (const float*)d_in[12];
  const float* w_bqkv  = (const float*)d_in[13];
  const float* w_rel   = (const float*)d_in[14];
  const float* w_gsim  = (const float*)d_in[15];
  const float* w_gout  = (const float*)d_in[17];
  const float* w_bout  = (const float*)d_in[18];
  const float* ln2w    = (const float*)d_in[19];
  const float* ln2b    = (const float*)d_in[20];
  const float* ffn_win = (const float*)d_in[21];
  const float* ffn_wdw = (const float*)d_in[22];
  const float* ffn_wout= (const float*)d_in[23];
  float* out = (float*)d_out;

  float* ws = (float*)d_ws;
  float* P = ws;
  float* Q = ws + 3538944;
  float* R = ws + 7077888;
  float* S = ws + 14155776;
  float* Gall = R;
  float* Hbuf = ws + 16478208;
  const size_t base_need = (21233664ull + 8192ull) * 4ull;
  const size_t big_need  = (35278848ull + 8192ull) * 4ull;
  if (ws_size < base_need) return;
  const bool batched = (ws_size >= big_need);
  float* stats = batched ? (ws + 35278848) : (ws + 21233664);

  float2* qkv_aff = (float2*)stats;
  float2* out_aff = (float2*)(stats + 384);
  float*  sim_st  = stats + 768;
  float*  sim_sc  = stats + 864;
  float*  tbl     = stats + 1024;

  hipMemsetAsync(sim_st, 0, 96 * sizeof(float), stream);

  dim3 b256(256), b1616(16, 16), b328(32, 8);

  ln_kernel<<<576, b256, 0, stream>>>(x, P, ln1w, ln1b);
  trans_kernel<<<dim3(3, 3, 384), b328, 0, stream>>>(P, Q);

  // ---- pass 1 (attention along H) ----
  gemm_kernel<96, 128, 0><<<dim3(288, 2, 1), b1616, 0, stream>>>(h_wqkv, Q, R,
      192, 96, 36864, 36864L, 0L, 0, nullptr, nullptr);
  rowstat_kernel<<<192, 1024, 0, stream>>>(R, h_gqkv, h_bqkv, qkv_aff);
  relstat_kernel<<<54, 96, 0, stream>>>(h_rel, tbl);
  simstat2_kernel<<<384, b256, 0, stream>>>(R, qkv_aff, tbl, sim_st);
  simfin_kernel<<<1, 32, 0, stream>>>(sim_st, h_gsim, sim_sc);
  attn_kernel<<<3072, b256, 0, stream>>>(R, qkv_aff, h_rel, sim_sc, S);
  rowstat_kernel<<<192, 1024, 0, stream>>>(S, h_gout, h_bout, out_aff);
  apply1_kernel<<<dim3(3, 3, 384), b328, 0, stream>>>(S, out_aff, P);

  // ---- pass 2 (attention along W) ----
  gemm_kernel<96, 128, 0><<<dim3(72, 2, 4), b1616, 0, stream>>>(w_wqkv, P, R,
      192, 96, 9216, 9216L, 884736L, 0, nullptr, nullptr);
  rowstat_kernel<<<192, 1024, 0, stream>>>(R, w_gqkv, w_bqkv, qkv_aff);
  relstat_kernel<<<54, 96, 0, stream>>>(w_rel, tbl);
  simstat2_kernel<<<384, b256, 0, stream>>>(R, qkv_aff, tbl, sim_st + 48);
  simfin_kernel<<<1, 32, 0, stream>>>(sim_st + 48, w_gsim, sim_sc + 24);
  attn_kernel<<<3072, b256, 0, stream>>>(R, qkv_aff, w_rel, sim_sc + 24, S);
  rowstat_kernel<<<192, 1024, 0, stream>>>(S, w_gout, w_bout, out_aff);
  // fused BN-apply + residual + ln2: writes X1 -> P and ln2 out -> Q
  apl2_kernel<<<576, b256, 0, stream>>>(S, out_aff, x, ln2w, ln2b, P, Q);

  // ---- FFN ----
  if (batched) {
    gemm_kernel<128, 64, 0><<<dim3(144, 4, 4), b1616, 0, stream>>>(ffn_win, Q, Hbuf,
        510, 96, 9216, 9216L, 884736L, 0, nullptr, nullptr);
    dwglu4_kernel<<<36720, b256, 0, stream>>>(Hbuf, ffn_wdw, Gall);
  } else {
    for (int n = 0; n < NB; n++) {
      gemm_kernel<128, 64, 0><<<dim3(144, 4, 1), b1616, 0, stream>>>(ffn_win, Q + (long)n * N_ST, Hbuf,
          510, 96, 9216, 9216L, 0L, 0, nullptr, nullptr);
      dwglu_kernel<<<9180, b256, 0, stream>>>(Hbuf, ffn_wdw, Gall + (long)n * 2350080);
    }
  }
  gemm_kernel<96, 64, 1><<<dim3(144, 1, 4), b1616, 0, stream>>>(ffn_wout, Gall, nullptr,
      96, 255, 9216, 9216L, 2350080L, 0, P, out);
}